// Round 10
// baseline (237.864 us; speedup 1.0000x reference)
//
#include <hip/hip_runtime.h>
#include <hip/hip_bf16.h>
#include <math.h>

typedef _Float16 f16;
typedef _Float16 f16x4 __attribute__((ext_vector_type(4)));
typedef _Float16 f16x8 __attribute__((ext_vector_type(8)));
typedef float f32x4 __attribute__((ext_vector_type(4)));

#define MIDC 256
#define NHEADS 8
#define HEADC 32
#define HW_ 4096
#define BATCH 8
#define NTOK (BATCH*HW_)   // 32768

__device__ __forceinline__ void gload_lds16(const void* g, void* lds){
    __builtin_amdgcn_global_load_lds(
        (const __attribute__((address_space(1))) unsigned int*)g,
        (__attribute__((address_space(3))) unsigned int*)lds, 16, 0, 0);
}

// ---------------- merged init: x->f16, weights -> per-64col-block k-major f16, bias permute ----
// weight image layout per 64-col block bx: elem[(bx*32 + k8)*64 + n)*8 + e] = W[k8*8+e][col bx*64+n]
__global__ void k_init(const float* __restrict__ x, const float* __restrict__ wqkv,
                       const float* __restrict__ w1, const float* __restrict__ w2,
                       const float* __restrict__ bq,
                       f16* __restrict__ xb, f16* __restrict__ wqkvK,
                       f16* __restrict__ w1K, f16* __restrict__ w2K, float* __restrict__ pb){
    int t = blockIdx.x*blockDim.x + threadIdx.x;
    if (t < 2097152){
        int i = t*4;
        float4 v = *reinterpret_cast<const float4*>(x + i);
        f16x4 o = { (f16)v.x, (f16)v.y, (f16)v.z, (f16)v.w };
        *reinterpret_cast<f16x4*>(xb + i) = o;
    } else {
        int j = t - 2097152;
        if (j < 196608){                     // wqkv [256 k][768 o] -> permuted k-major blocks
            int k = j / 768, o = j % 768;
            int h = o / 96, rr = o % 96, p = rr >> 5, d = o & 31;
            int np = (p << 8) + (h << 5) + d;          // permuted col: q|k|v contiguous
            wqkvK[((((np>>6)*32) + (k>>3))*64 + (np&63))*8 + (k&7)] = (f16)wqkv[j];
        } else if (j < 262144){              // w1 [256 k][256 c]
            int i2 = j - 196608; int k = i2 >> 8, c = i2 & 255;
            w1K[((((c>>6)*32) + (k>>3))*64 + (c&63))*8 + (k&7)] = (f16)w1[i2];
        } else if (j < 327680){              // w2
            int i2 = j - 262144; int k = i2 >> 8, c = i2 & 255;
            w2K[((((c>>6)*32) + (k>>3))*64 + (c&63))*8 + (k&7)] = (f16)w2[i2];
        } else if (j < 328448){              // bias permute
            int n = j - 327680;
            int p = n >> 8, h = (n & 255) >> 5, d = n & 31;
            pb[n] = bq[h*96 + p*32 + d];
        }
    }
}

// ---------------- GEMM: C[M,Ncols] = A[M,256] f16 x W, 128x64 block, B-in-LDS-once, barrier-free K-stream
// MODE 0: +bias(permuted), LN on k/v heads, coalesced scatter q/k/v [B,H,HW,32] f16
// MODE 1: +bias, exact GELU -> oh f16 [M,256]
// MODE 2: +bias, +resid f16 -> of f32 [M,256]
template<int MODE, int GX>
__global__ __launch_bounds__(256, 4) void k_gemm(
    const f16* __restrict__ A, const f16* __restrict__ Bk,
    const float* __restrict__ bias,
    const float* __restrict__ kg_, const float* __restrict__ kb_,
    const float* __restrict__ vg_, const float* __restrict__ vb_,
    f16* __restrict__ oq, f16* __restrict__ ok, f16* __restrict__ ov,
    f16* __restrict__ oh,
    const f16* __restrict__ residh, float* __restrict__ of)
{
    __shared__ __attribute__((aligned(16))) char smem[32768];
    f16* Bs = (f16*)smem;                  // [k8 0..31][n 0..63][e 0..7] f16 (= 32 KB)

    const int tid  = threadIdx.x;
    const int lane = tid & 63, wid = tid >> 6;

    // XCD-chunked bijective swizzle (nwg % 8 == 0)
    const int nwg  = GX * 256;
    const int orig = blockIdx.x + GX*blockIdx.y;
    const int lin  = (orig & 7) * (nwg >> 3) + (orig >> 3);
    const int bx = lin % GX, by = lin / GX;
    const int m0 = by * 128, n0 = bx * 64;

    const int wm = (wid >> 1) * 64;        // {0,64}
    const int wn = (wid & 1) * 32;         // {0,32}
    const int lr = lane & 15, kg = lane >> 4;

    // ---- stage entire B block (64 cols x K=256) once: contiguous 32 KB copy ----
    {
        const f16* gB = Bk + (size_t)bx*16384;     // 16384 f16 per block
        char* dst = smem + wid*1024;               // + lane*16 implicit
        #pragma unroll
        for (int j=0; j<8; ++j)
            gload_lds16(gB + j*2048 + tid*8, dst + j*4096);
    }

    f32x4 acc[4][2];
    #pragma unroll
    for (int i=0;i<4;i++)
        #pragma unroll
        for (int j=0;j<2;j++) acc[i][j] = (f32x4){0.f,0.f,0.f,0.f};

    const f16* gA = A + (size_t)(m0 + wm + lr)*256 + kg*8;

    __syncthreads();   // B resident (drains the gload_lds)

    // ---- barrier-free K stream: depth-1 pipelined A loads, B from LDS ----
    f16x8 ac[4], an[4];
    #pragma unroll
    for (int fr=0; fr<4; ++fr)
        ac[fr] = *reinterpret_cast<const f16x8*>(gA + fr*4096);
    #pragma unroll
    for (int kt=0; kt<8; ++kt){
        if (kt < 7){
            #pragma unroll
            for (int fr=0; fr<4; ++fr)
                an[fr] = *reinterpret_cast<const f16x8*>(gA + fr*4096 + (kt+1)*32);
        }
        const int k8 = kt*4 + kg;
        f16x8 bf0 = *reinterpret_cast<const f16x8*>(Bs + ((k8*64) + wn      + lr)*8);
        f16x8 bf1 = *reinterpret_cast<const f16x8*>(Bs + ((k8*64) + wn + 16 + lr)*8);
        #pragma unroll
        for (int fr=0; fr<4; ++fr){
            acc[fr][0] = __builtin_amdgcn_mfma_f32_16x16x32_f16(ac[fr], bf0, acc[fr][0], 0, 0, 0);
            acc[fr][1] = __builtin_amdgcn_mfma_f32_16x16x32_f16(ac[fr], bf1, acc[fr][1], 0, 0, 0);
        }
        if (kt < 7){
            #pragma unroll
            for (int fr=0; fr<4; ++fr) ac[fr] = an[fr];
        }
    }

    float bv[2];
    #pragma unroll
    for (int fc=0; fc<2; fc++) bv[fc] = bias[n0 + wn + fc*16 + lr];

    if constexpr (MODE != 2){
        // ---- stage acc -> Cs[128][72] f16 (bias [+gelu]), coalesced 64B epilogue ----
        __syncthreads();                   // all waves done reading Bs
        f16* Cs = (f16*)smem;
        #pragma unroll
        for (int fr=0; fr<4; fr++)
        #pragma unroll
        for (int fc=0; fc<2; fc++)
        #pragma unroll
        for (int r=0; r<4; r++){
            float v = acc[fr][fc][r] + bv[fc];
            if constexpr (MODE == 1) v = 0.5f * v * (1.0f + erff(v * 0.70710678f));
            Cs[(wm + fr*16 + kg*4 + r)*72 + (wn + fc*16 + lr)] = (f16)v;
        }
        __syncthreads();
        int row = tid >> 1, ch = tid & 1;
        const f16* src = Cs + row*72 + ch*32;
        f16x8 d0 = *reinterpret_cast<const f16x8*>(src);
        f16x8 d1 = *reinterpret_cast<const f16x8*>(src + 8);
        f16x8 d2 = *reinterpret_cast<const f16x8*>(src + 16);
        f16x8 d3 = *reinterpret_cast<const f16x8*>(src + 24);
        int gm = m0 + row;
        if constexpr (MODE == 0){
            int part = n0 >> 8;                    // block-uniform
            int col0 = n0 + ch*32;
            int h = (col0 & 255) >> 5;
            int b = gm >> 12, n = gm & 4095;
            f16* dst = (part==0 ? oq : (part==1 ? ok : ov))
                     + ((size_t)(b*NHEADS + h)*HW_ + n)*HEADC;
            if (part == 0){
                *reinterpret_cast<f16x8*>(dst)      = d0;
                *reinterpret_cast<f16x8*>(dst + 8)  = d1;
                *reinterpret_cast<f16x8*>(dst + 16) = d2;
                *reinterpret_cast<f16x8*>(dst + 24) = d3;
            } else {
                float vals[32];
                #pragma unroll
                for (int j=0;j<8;j++){
                    vals[j]    = (float)d0[j];
                    vals[8+j]  = (float)d1[j];
                    vals[16+j] = (float)d2[j];
                    vals[24+j] = (float)d3[j];
                }
                float s = 0.f, s2 = 0.f;
                #pragma unroll
                for (int j=0;j<32;j++){ s += vals[j]; s2 = fmaf(vals[j], vals[j], s2); }
                float mu  = s * (1.0f/32.0f);
                float var = s2 * (1.0f/32.0f) - mu*mu;
                float rs  = rsqrtf(var + 1e-5f);
                const float* gp = (part==1) ? kg_ : vg_;
                const float* bp = (part==1) ? kb_ : vb_;
                f16x8 o0, o1, o2, o3;
                #pragma unroll
                for (int j=0;j<8;j++){
                    o0[j] = (f16)((vals[j]    - mu)*rs*gp[j]    + bp[j]);
                    o1[j] = (f16)((vals[8+j]  - mu)*rs*gp[8+j]  + bp[8+j]);
                    o2[j] = (f16)((vals[16+j] - mu)*rs*gp[16+j] + bp[16+j]);
                    o3[j] = (f16)((vals[24+j] - mu)*rs*gp[24+j] + bp[24+j]);
                }
                *reinterpret_cast<f16x8*>(dst)      = o0;
                *reinterpret_cast<f16x8*>(dst + 8)  = o1;
                *reinterpret_cast<f16x8*>(dst + 16) = o2;
                *reinterpret_cast<f16x8*>(dst + 24) = o3;
            }
        } else { // MODE 1
            f16* dst = oh + (size_t)gm*MIDC + n0 + ch*32;
            *reinterpret_cast<f16x8*>(dst)      = d0;
            *reinterpret_cast<f16x8*>(dst + 8)  = d1;
            *reinterpret_cast<f16x8*>(dst + 16) = d2;
            *reinterpret_cast<f16x8*>(dst + 24) = d3;
        }
    } else {
        // ---- MODE 2: direct f32 stores + f16 residual ----
        #pragma unroll
        for (int fr=0; fr<4; fr++)
        #pragma unroll
        for (int fc=0; fc<2; fc++)
        #pragma unroll
        for (int r=0; r<4; r++){
            int gm = m0 + wm + fr*16 + kg*4 + r;
            int gn = n0 + wn + fc*16 + lr;
            size_t xi = (size_t)gm*MIDC + gn;
            of[xi] = acc[fr][fc][r] + bv[fc] + (float)residh[xi];
        }
    }
}

// ---------------- kv partials: per (bh, chunk of 256 tokens), 4 waves x 64 tokens ----------------
__global__ __launch_bounds__(256) void k_kv(const f16* __restrict__ kb, const f16* __restrict__ vb,
                                            float* __restrict__ kvpart){
    __shared__ __attribute__((aligned(16))) char sm[32768];
    f16* ks = (f16*)sm;                 // [4][64][32] f16 = 16384 B
    f16* vs = (f16*)(sm + 16384);       // 16384 B
    float* red = (float*)sm;            // [4][32][32] f32, overlays ks after barrier
    const int bh = blockIdx.x, chunk = blockIdx.y;
    const int tid = threadIdx.x, lane = tid & 63, wid = tid >> 6;
    const int d0 = (lane >> 3) * 4, e0 = (lane & 7) * 4;
    const int tok0 = chunk*256 + wid*64;

    const f16* kg = kb + ((size_t)bh*HW_ + tok0)*HEADC;
    const f16* vg = vb + ((size_t)bh*HW_ + tok0)*HEADC;
    f16* ksw = ks + wid*2048; f16* vsw = vs + wid*2048;
    #pragma unroll
    for (int i=0;i<4;i++){
        gload_lds16(kg + (size_t)(i*16 + (lane>>2))*HEADC + (lane&3)*8, ksw + i*512);
        gload_lds16(vg + (size_t)(i*16 + (lane>>2))*HEADC + (lane&3)*8, vsw + i*512);
    }
    __syncthreads();

    f32x4 acc[4];
    #pragma unroll
    for (int i=0;i<4;i++) acc[i] = (f32x4){0.f,0.f,0.f,0.f};
    #pragma unroll 4
    for (int t=0; t<64; t++){
        f16x4 kk = *reinterpret_cast<const f16x4*>(ks + wid*2048 + t*32 + d0);
        f16x4 vv = *reinterpret_cast<const f16x4*>(vs + wid*2048 + t*32 + e0);
        f32x4 vf = { (float)vv[0], (float)vv[1], (float)vv[2], (float)vv[3] };
        #pragma unroll
        for (int i=0;i<4;i++) acc[i] += (float)kk[i] * vf;
    }
    __syncthreads();
    #pragma unroll
    for (int i=0;i<4;i++) *reinterpret_cast<f32x4*>(red + wid*1024 + (d0+i)*32 + e0) = acc[i];
    __syncthreads();
    int de0 = tid * 4;
    f32x4 s = *reinterpret_cast<const f32x4*>(red + de0);
    #pragma unroll
    for (int w=1; w<4; w++) s += *reinterpret_cast<const f32x4*>(red + w*1024 + de0);
    *reinterpret_cast<f32x4*>(kvpart + ((size_t)bh*16 + chunk)*1024 + de0) = s;
}

// ---------------- reduce partials -> kvT f16 [bh][e][d], scaled 1/HW ----------------
__global__ void k_kvred(const float* __restrict__ kvpart, f16* __restrict__ kvT){
    int gid = blockIdx.x*blockDim.x + threadIdx.x; // 65536
    int bh = gid >> 10, de = gid & 1023;
    int d = de >> 5, e = de & 31;
    float s = 0.f;
    #pragma unroll
    for (int p=0; p<16; p++) s += kvpart[((size_t)bh*16 + p)*1024 + de];
    kvT[((size_t)bh << 10) + (e << 5) + d] = (f16)(s * (1.0f/4096.0f));
}

// ---------------- attn: ret = q @ kvT^T + xb, MFMA + LDS-staged coalesced epilogue ----------------
__global__ __launch_bounds__(256) void k_attn(const f16* __restrict__ qb, const f16* __restrict__ kvT,
                                              const f16* __restrict__ xb, f16* __restrict__ ret){
    __shared__ __attribute__((aligned(16))) f16 Ls[128][40];
    const int bh = blockIdx.x, chunk = blockIdx.y;
    const int b = bh >> 3, h = bh & 7;
    const int tid = threadIdx.x, lane = tid & 63, wid = tid >> 6;
    const int lr = lane & 15, kg = lane >> 4;
    const int row0 = chunk*128 + wid*32;

    f32x4 acc[2][2];
    #pragma unroll
    for (int i=0;i<2;i++)
        #pragma unroll
        for (int j=0;j<2;j++) acc[i][j] = (f32x4){0.f,0.f,0.f,0.f};

    f16x8 a[2], bb[2];
    #pragma unroll
    for (int fr=0; fr<2; fr++)
        a[fr] = *reinterpret_cast<const f16x8*>(qb + ((size_t)bh*HW_ + row0 + fr*16 + lr)*HEADC + kg*8);
    #pragma unroll
    for (int fc=0; fc<2; fc++)
        bb[fc] = *reinterpret_cast<const f16x8*>(kvT + ((size_t)bh << 10) + (size_t)(fc*16 + lr)*32 + kg*8);
    #pragma unroll
    for (int fr=0; fr<2; fr++)
        #pragma unroll
        for (int fc=0; fc<2; fc++)
            acc[fr][fc] = __builtin_amdgcn_mfma_f32_16x16x32_f16(a[fr], bb[fc], acc[fr][fc], 0, 0, 0);

    #pragma unroll
    for (int fr=0; fr<2; fr++)
    #pragma unroll
    for (int fc=0; fc<2; fc++)
    #pragma unroll
    for (int r=0; r<4; r++)
        Ls[wid*32 + fr*16 + kg*4 + r][fc*16 + lr] = (f16)acc[fr][fc][r];
    __syncthreads();

    int row = tid >> 1, hf = tid & 1;
    size_t base = ((size_t)b*HW_ + chunk*128 + row)*MIDC + h*HEADC + hf*16;
    f16x8 x0 = *reinterpret_cast<const f16x8*>(xb + base);
    f16x8 x1 = *reinterpret_cast<const f16x8*>(xb + base + 8);
    f16x8 s0 = *reinterpret_cast<const f16x8*>(&Ls[row][hf*16]);
    f16x8 s1 = *reinterpret_cast<const f16x8*>(&Ls[row][hf*16 + 8]);
    f16x8 o0, o1;
    #pragma unroll
    for (int j=0;j<8;j++){
        o0[j] = (f16)((float)s0[j] + (float)x0[j]);
        o1[j] = (f16)((float)s1[j] + (float)x1[j]);
    }
    *reinterpret_cast<f16x8*>(ret + base)     = o0;
    *reinterpret_cast<f16x8*>(ret + base + 8) = o1;
}

extern "C" void kernel_launch(void* const* d_in, const int* in_sizes, int n_in,
                              void* d_out, int out_size, void* d_ws, size_t ws_size,
                              hipStream_t stream) {
    const float* x     = (const float*)d_in[0];
    const float* w_qkv = (const float*)d_in[1];
    const float* b_qkv = (const float*)d_in[2];
    const float* kln_g = (const float*)d_in[3];
    const float* kln_b = (const float*)d_in[4];
    const float* vln_g = (const float*)d_in[5];
    const float* vln_b = (const float*)d_in[6];
    const float* w1    = (const float*)d_in[7];
    const float* b1    = (const float*)d_in[8];
    const float* w2    = (const float*)d_in[9];
    const float* b2    = (const float*)d_in[10];
    float* out = (float*)d_out;

    char* ws = (char*)d_ws;
    size_t off = 0;
    auto alloc = [&](size_t bytes) -> void* {
        void* p = ws + off; off += (bytes + 255) & ~255ULL; return p;
    };
    const size_t TOKB = (size_t)NTOK*MIDC*sizeof(f16); // 16.78 MB
    f16* xb    = (f16*)alloc(TOKB);               // preserved (residuals)
    f16* wqkvK = (f16*)alloc(196608*sizeof(f16)); // k-major blocked
    f16* w1K   = (f16*)alloc(65536*sizeof(f16));
    f16* w2K   = (f16*)alloc(65536*sizeof(f16));
    float* pb  = (float*)alloc(768*sizeof(float));
    f16* qb    = (f16*)alloc(TOKB);
    f16* kb    = (f16*)alloc(TOKB);               // reused as h after k_kv
    f16* vb    = (f16*)alloc(TOKB);               // reused as ret after k_kv
    float* kvpart = (float*)alloc((size_t)64*16*1024*sizeof(float)); // 4 MB
    f16* kvT   = (f16*)alloc((size_t)64*1024*sizeof(f16));
    f16* retb = vb;
    f16* hb   = kb;

    // 1. merged convert + weight prep (2097152 convert threads + 328448 prep threads)
    k_init<<<dim3(9475), 256, 0, stream>>>(x, w_qkv, w1, w2, b_qkv, xb, wqkvK, w1K, w2K, pb);

    // 2. QKV GEMM + bias + LN(k,v) + coalesced scatter
    k_gemm<0,12><<<dim3(12, NTOK/128), 256, 0, stream>>>(
        xb, wqkvK, pb, kln_g, kln_b, vln_g, vln_b,
        qb, kb, vb, nullptr, nullptr, nullptr);

    // 3. kv partials + reduce (-> kvT, pre-scaled, transposed)
    k_kv<<<dim3(64, HW_/256), 256, 0, stream>>>(kb, vb, kvpart);
    k_kvred<<<dim3(65536/256), 256, 0, stream>>>(kvpart, kvT);

    // 4. attn + residual(xb f16) -> ret f16 (into vb space)
    k_attn<<<dim3(64, HW_/128), 256, 0, stream>>>(qb, kvT, xb, retb);

    // 5. MLP1 (+GELU) -> h (into kb space)
    k_gemm<1,4><<<dim3(4, NTOK/128), 256, 0, stream>>>(
        retb, w1K, b1, nullptr, nullptr, nullptr, nullptr,
        nullptr, nullptr, nullptr, hb, nullptr, nullptr);

    // 6. MLP2 (+bias +resid xb) -> f32 out
    k_gemm<2,4><<<dim3(4, NTOK/128), 256, 0, stream>>>(
        hb, w2K, b2, nullptr, nullptr, nullptr, nullptr,
        nullptr, nullptr, nullptr, nullptr, xb, out);
}

// Round 11
// 193.699 us; speedup vs baseline: 1.2280x; 1.2280x over previous
//
#include <hip/hip_runtime.h>
#include <hip/hip_bf16.h>
#include <math.h>

typedef _Float16 f16;
typedef _Float16 f16x4 __attribute__((ext_vector_type(4)));
typedef _Float16 f16x8 __attribute__((ext_vector_type(8)));
typedef float f32x4 __attribute__((ext_vector_type(4)));

#define MIDC 256
#define NHEADS 8
#define HEADC 32
#define HW_ 4096
#define BATCH 8
#define NTOK (BATCH*HW_)   // 32768

__device__ __forceinline__ void gload_lds16(const void* g, void* lds){
    __builtin_amdgcn_global_load_lds(
        (const __attribute__((address_space(1))) unsigned int*)g,
        (__attribute__((address_space(3))) unsigned int*)lds, 16, 0, 0);
}

// ---------------- merged init: x->f16 + weight transposes + bias permute ----------------
__global__ void k_init(const float* __restrict__ x, const float* __restrict__ wqkv,
                       const float* __restrict__ w1, const float* __restrict__ w2,
                       const float* __restrict__ bq,
                       f16* __restrict__ xb, f16* __restrict__ wqkvT,
                       f16* __restrict__ w1T, f16* __restrict__ w2T, float* __restrict__ pb){
    int t = blockIdx.x*blockDim.x + threadIdx.x;
    if (t < 2097152){
        int i = t*4;
        float4 v = *reinterpret_cast<const float4*>(x + i);
        f16x4 o = { (f16)v.x, (f16)v.y, (f16)v.z, (f16)v.w };
        *reinterpret_cast<f16x4*>(xb + i) = o;
    } else {
        int j = t - 2097152;
        if (j < 196608){                     // wqkv [256][768] -> [768p][256]
            int r = j / 768, o = j % 768;
            int h = o / 96, rr = o % 96, p = rr >> 5, d = o & 31;
            int n = (p << 8) + (h << 5) + d;
            wqkvT[(size_t)n*256 + r] = (f16)wqkv[j];
        } else if (j < 262144){              // w1 [256][256] -> T
            int i2 = j - 196608; int r = i2 >> 8, c = i2 & 255;
            w1T[(size_t)c*256 + r] = (f16)w1[i2];
        } else if (j < 327680){              // w2
            int i2 = j - 262144; int r = i2 >> 8, c = i2 & 255;
            w2T[(size_t)c*256 + r] = (f16)w2[i2];
        } else if (j < 328448){              // bias permute
            int n = j - 327680;
            int p = n >> 8, h = (n & 255) >> 5, d = n & 31;
            pb[n] = bq[h*96 + p*32 + d];
        }
    }
}

// ---------------- GEMM0: qkv = x@Wqkv, 128x128 tile, 256 thr, 32 KB LDS (5 blocks/CU) ----------------
__global__ __launch_bounds__(256) void k_gemm0(
    const f16* __restrict__ A, const f16* __restrict__ Bt,
    const float* __restrict__ bias,
    const float* __restrict__ kg_, const float* __restrict__ kb_,
    const float* __restrict__ vg_, const float* __restrict__ vb_,
    f16* __restrict__ oq, f16* __restrict__ ok, f16* __restrict__ ov)
{
    constexpr int K = 256;
    __shared__ __attribute__((aligned(16))) char smem[32768];  // 2 bufs x (A 8K | B 8K)

    const int tid  = threadIdx.x;
    const int lane = tid & 63, wid = tid >> 6;

    // XCD-chunked bijective swizzle (nwg = 1536, %8 == 0)
    const int nwg  = 6 * 256;
    const int orig = blockIdx.x + 6*blockIdx.y;
    const int lin  = (orig & 7) * (nwg >> 3) + (orig >> 3);
    const int bx = lin % 6, by = lin / 6;
    const int m0 = by * 128, n0 = bx * 128;

    const int wm = (wid >> 1) * 64, wn = (wid & 1) * 64;
    const int lr = lane & 15, kg = lane >> 4;

    f32x4 acc[4][4];
    #pragma unroll
    for (int i=0;i<4;i++)
        #pragma unroll
        for (int j=0;j<4;j++) acc[i][j] = (f32x4){0.f,0.f,0.f,0.f};

    const int srow = tid >> 2, scol = (tid & 3) * 8;
    const f16* gA = A  + (size_t)(m0 + srow)*K + scol;
    const f16* gB = Bt + (size_t)(n0 + srow)*K + scol;
    const size_t rstep = (size_t)64*K;

    auto STAGE = [&](int b, int kt){
        f16* base = (f16*)smem + b*8192;
        f16* ab = base + wid*512;
        f16* bb = base + 4096 + wid*512;
        gload_lds16(gA + kt,          ab);
        gload_lds16(gA + kt + rstep,  ab + 2048);
        gload_lds16(gB + kt,          bb);
        gload_lds16(gB + kt + rstep,  bb + 2048);
    };

    STAGE(0, 0);
    __syncthreads();
    #pragma unroll
    for (int t = 0; t < 8; ++t){
        const int cur = t & 1;
        if (t < 7) STAGE(cur ^ 1, (t+1)*32);
        const f16* Ac = (const f16*)smem + cur*8192;
        const f16* Bc = Ac + 4096;
        f16x8 a[4], b[4];
        #pragma unroll
        for (int fr=0; fr<4; fr++) a[fr] = *reinterpret_cast<const f16x8*>(Ac + (wm + fr*16 + lr)*32 + kg*8);
        #pragma unroll
        for (int fc=0; fc<4; fc++) b[fc] = *reinterpret_cast<const f16x8*>(Bc + (wn + fc*16 + lr)*32 + kg*8);
        #pragma unroll
        for (int fr=0; fr<4; fr++)
            #pragma unroll
            for (int fc=0; fc<4; fc++)
                acc[fr][fc] = __builtin_amdgcn_mfma_f32_16x16x32_f16(a[fr], b[fc], acc[fr][fc], 0, 0, 0);
        __syncthreads();
    }

    // -------- two half-passes: acc -> Cs[64][132] f16 (bias), coalesced LN/scatter --------
    f16* Cs = (f16*)smem;           // 16896 B, all bufs dead
    float bv[4];
    #pragma unroll
    for (int fc=0; fc<4; fc++) bv[fc] = bias[n0 + wn + fc*16 + lr];
    const int part = n0 >> 8;       // block-uniform: 0=q, 1=k, 2=v
    #pragma unroll
    for (int half=0; half<2; ++half){
        if (half) __syncthreads();  // half-0 readers done before overwrite
        if ((wid >> 1) == half){    // waves owning rows [half*64, half*64+64)
            #pragma unroll
            for (int fr=0; fr<4; fr++)
            #pragma unroll
            for (int fc=0; fc<4; fc++)
            #pragma unroll
            for (int r=0; r<4; r++){
                float v = acc[fr][fc][r] + bv[fc];
                Cs[(fr*16 + kg*4 + r)*132 + (wn + fc*16 + lr)] = (f16)v;
            }
        }
        __syncthreads();
        int row = tid >> 2, hc = tid & 3;     // row 0..63
        const f16* src = Cs + row*132 + hc*32;
        f16x8 d0 = *reinterpret_cast<const f16x8*>(src);
        f16x8 d1 = *reinterpret_cast<const f16x8*>(src + 8);
        f16x8 d2 = *reinterpret_cast<const f16x8*>(src + 16);
        f16x8 d3 = *reinterpret_cast<const f16x8*>(src + 24);
        int gm = m0 + half*64 + row;
        int col0 = n0 + hc*32;
        int h = (col0 & 255) >> 5;
        int b = gm >> 12, n = gm & 4095;
        f16* dst = (part==0 ? oq : (part==1 ? ok : ov))
                 + ((size_t)(b*NHEADS + h)*HW_ + n)*HEADC;
        if (part == 0){
            *reinterpret_cast<f16x8*>(dst)      = d0;
            *reinterpret_cast<f16x8*>(dst + 8)  = d1;
            *reinterpret_cast<f16x8*>(dst + 16) = d2;
            *reinterpret_cast<f16x8*>(dst + 24) = d3;
        } else {
            float vals[32];
            #pragma unroll
            for (int j=0;j<8;j++){
                vals[j]    = (float)d0[j];
                vals[8+j]  = (float)d1[j];
                vals[16+j] = (float)d2[j];
                vals[24+j] = (float)d3[j];
            }
            float s = 0.f, s2 = 0.f;
            #pragma unroll
            for (int j=0;j<32;j++){ s += vals[j]; s2 = fmaf(vals[j], vals[j], s2); }
            float mu  = s * (1.0f/32.0f);
            float var = s2 * (1.0f/32.0f) - mu*mu;
            float rs  = rsqrtf(var + 1e-5f);
            const float* gp = (part==1) ? kg_ : vg_;
            const float* bp = (part==1) ? kb_ : vb_;
            f16x8 o0, o1, o2, o3;
            #pragma unroll
            for (int j=0;j<8;j++){
                o0[j] = (f16)((vals[j]    - mu)*rs*gp[j]    + bp[j]);
                o1[j] = (f16)((vals[8+j]  - mu)*rs*gp[8+j]  + bp[8+j]);
                o2[j] = (f16)((vals[16+j] - mu)*rs*gp[16+j] + bp[16+j]);
                o3[j] = (f16)((vals[24+j] - mu)*rs*gp[24+j] + bp[24+j]);
            }
            *reinterpret_cast<f16x8*>(dst)      = o0;
            *reinterpret_cast<f16x8*>(dst + 8)  = o1;
            *reinterpret_cast<f16x8*>(dst + 16) = o2;
            *reinterpret_cast<f16x8*>(dst + 24) = o3;
        }
    }
}

// ---------------- MLP GEMM: 128x64 tile, 256 thr, 24 KB LDS (6 blocks/CU) — R8-proven ----------------
// MODE 1: +bias, exact GELU -> oh f16 [M,256]
// MODE 2: +bias, +resid f16 -> of f32 [M,256]
template<int MODE>
__global__ __launch_bounds__(256, 4) void k_mlp(
    const f16* __restrict__ A, const f16* __restrict__ Bt,
    const float* __restrict__ bias,
    f16* __restrict__ oh,
    const f16* __restrict__ residh, float* __restrict__ of)
{
    constexpr int K = 256;
    __shared__ __attribute__((aligned(16))) char smem[24576];

    const int tid  = threadIdx.x;
    const int lane = tid & 63, wid = tid >> 6;

    const int nwg  = 4 * 256;
    const int orig = blockIdx.x + 4*blockIdx.y;
    const int lin  = (orig & 7) * (nwg >> 3) + (orig >> 3);
    const int bx = lin & 3, by = lin >> 2;
    const int m0 = by * 128, n0 = bx * 64;

    const int wm = (wid >> 1) * 64;    // {0,64}
    const int wn = (wid & 1) * 32;     // {0,32}
    const int lr = lane & 15, kg = lane >> 4;

    f32x4 acc[4][2];
    #pragma unroll
    for (int i=0;i<4;i++)
        #pragma unroll
        for (int j=0;j<2;j++) acc[i][j] = (f32x4){0.f,0.f,0.f,0.f};

    const int srow = tid >> 2, scol = (tid & 3) * 8;
    const f16* gA = A  + (size_t)(m0 + srow)*K + scol;
    const f16* gB = Bt + (size_t)(n0 + srow)*K + scol;

    auto STAGE = [&](int b, int kt){
        f16* Ab = (f16*)(smem + b*12288);
        f16* Bb = Ab + 4096;
        gload_lds16(gA + kt,                 Ab + wid*512);
        gload_lds16(gA + kt + (size_t)64*K,  Ab + 2048 + wid*512);
        gload_lds16(gB + kt,                 Bb + wid*512);
    };

    STAGE(0, 0);
    __syncthreads();
    #pragma unroll
    for (int t = 0; t < 8; ++t){
        const int cur = t & 1;
        if (t < 7) STAGE(cur ^ 1, (t+1)*32);
        const f16* Ab = (const f16*)(smem + cur*12288);
        const f16* Bb = Ab + 4096;
        f16x8 a[4], bf[2];
        #pragma unroll
        for (int fr=0; fr<4; fr++) a[fr]  = *reinterpret_cast<const f16x8*>(Ab + (wm + fr*16 + lr)*32 + kg*8);
        #pragma unroll
        for (int fc=0; fc<2; fc++) bf[fc] = *reinterpret_cast<const f16x8*>(Bb + (wn + fc*16 + lr)*32 + kg*8);
        #pragma unroll
        for (int fr=0; fr<4; fr++)
            #pragma unroll
            for (int fc=0; fc<2; fc++)
                acc[fr][fc] = __builtin_amdgcn_mfma_f32_16x16x32_f16(a[fr], bf[fc], acc[fr][fc], 0, 0, 0);
        __syncthreads();
    }

    float bv[2];
    #pragma unroll
    for (int fc=0; fc<2; fc++) bv[fc] = bias[n0 + wn + fc*16 + lr];

    if constexpr (MODE == 1){
        f16* Cs = (f16*)smem;
        #pragma unroll
        for (int fr=0; fr<4; fr++)
        #pragma unroll
        for (int fc=0; fc<2; fc++)
        #pragma unroll
        for (int r=0; r<4; r++){
            float v = acc[fr][fc][r] + bv[fc];
            v = 0.5f * v * (1.0f + erff(v * 0.70710678f));
            Cs[(wm + fr*16 + kg*4 + r)*72 + (wn + fc*16 + lr)] = (f16)v;
        }
        __syncthreads();
        int row = tid >> 1, ch = tid & 1;
        const f16* src = Cs + row*72 + ch*32;
        f16x8 d0 = *reinterpret_cast<const f16x8*>(src);
        f16x8 d1 = *reinterpret_cast<const f16x8*>(src + 8);
        f16x8 d2 = *reinterpret_cast<const f16x8*>(src + 16);
        f16x8 d3 = *reinterpret_cast<const f16x8*>(src + 24);
        f16* dst = oh + (size_t)(m0 + row)*MIDC + n0 + ch*32;
        *reinterpret_cast<f16x8*>(dst)      = d0;
        *reinterpret_cast<f16x8*>(dst + 8)  = d1;
        *reinterpret_cast<f16x8*>(dst + 16) = d2;
        *reinterpret_cast<f16x8*>(dst + 24) = d3;
    } else {
        #pragma unroll
        for (int fr=0; fr<4; fr++)
        #pragma unroll
        for (int fc=0; fc<2; fc++)
        #pragma unroll
        for (int r=0; r<4; r++){
            int gm = m0 + wm + fr*16 + kg*4 + r;
            int gn = n0 + wn + fc*16 + lr;
            size_t xi = (size_t)gm*MIDC + gn;
            of[xi] = acc[fr][fc][r] + bv[fc] + (float)residh[xi];
        }
    }
}

// ---------------- kv partials: per (bh, chunk of 256 tokens), 4 waves x 64 tokens (R10-proven) ------
__global__ __launch_bounds__(256) void k_kv(const f16* __restrict__ kb, const f16* __restrict__ vb,
                                            float* __restrict__ kvpart){
    __shared__ __attribute__((aligned(16))) char sm[32768];
    f16* ks = (f16*)sm;
    f16* vs = (f16*)(sm + 16384);
    float* red = (float*)sm;            // overlays ks after barrier
    const int bh = blockIdx.x, chunk = blockIdx.y;
    const int tid = threadIdx.x, lane = tid & 63, wid = tid >> 6;
    const int d0 = (lane >> 3) * 4, e0 = (lane & 7) * 4;
    const int tok0 = chunk*256 + wid*64;

    const f16* kg = kb + ((size_t)bh*HW_ + tok0)*HEADC;
    const f16* vg = vb + ((size_t)bh*HW_ + tok0)*HEADC;
    f16* ksw = ks + wid*2048; f16* vsw = vs + wid*2048;
    #pragma unroll
    for (int i=0;i<4;i++){
        gload_lds16(kg + (size_t)(i*16 + (lane>>2))*HEADC + (lane&3)*8, ksw + i*512);
        gload_lds16(vg + (size_t)(i*16 + (lane>>2))*HEADC + (lane&3)*8, vsw + i*512);
    }
    __syncthreads();

    f32x4 acc[4];
    #pragma unroll
    for (int i=0;i<4;i++) acc[i] = (f32x4){0.f,0.f,0.f,0.f};
    #pragma unroll 4
    for (int t=0; t<64; t++){
        f16x4 kk = *reinterpret_cast<const f16x4*>(ks + wid*2048 + t*32 + d0);
        f16x4 vv = *reinterpret_cast<const f16x4*>(vs + wid*2048 + t*32 + e0);
        f32x4 vf = { (float)vv[0], (float)vv[1], (float)vv[2], (float)vv[3] };
        #pragma unroll
        for (int i=0;i<4;i++) acc[i] += (float)kk[i] * vf;
    }
    __syncthreads();
    #pragma unroll
    for (int i=0;i<4;i++) *reinterpret_cast<f32x4*>(red + wid*1024 + (d0+i)*32 + e0) = acc[i];
    __syncthreads();
    int de0 = tid * 4;
    f32x4 s = *reinterpret_cast<const f32x4*>(red + de0);
    #pragma unroll
    for (int w=1; w<4; w++) s += *reinterpret_cast<const f32x4*>(red + w*1024 + de0);
    *reinterpret_cast<f32x4*>(kvpart + ((size_t)bh*16 + chunk)*1024 + de0) = s;
}

// ---------------- attn (+fused kv reduce): ret = q @ kv + xb ----------------
__global__ __launch_bounds__(256) void k_attn(const f16* __restrict__ qb, const float* __restrict__ kvpart,
                                              const f16* __restrict__ xb, f16* __restrict__ ret){
    __shared__ __attribute__((aligned(16))) f16 kvs[32][40];   // [e][d] f16, pre-scaled
    __shared__ __attribute__((aligned(16))) f16 Ls[128][40];
    const int bh = blockIdx.x, chunk = blockIdx.y;
    const int b = bh >> 3, h = bh & 7;
    const int tid = threadIdx.x, lane = tid & 63, wid = tid >> 6;
    const int lr = lane & 15, kg = lane >> 4;
    const int row0 = chunk*128 + wid*32;

    // fused kvpart reduce -> kvs[e][d]
    {
        int de0 = tid * 4;
        const float* base = kvpart + (size_t)bh*16384 + de0;
        f32x4 s = *reinterpret_cast<const f32x4*>(base);
        #pragma unroll
        for (int p=1; p<16; p++) s += *reinterpret_cast<const f32x4*>(base + p*1024);
        int d = de0 >> 5, e0 = de0 & 31;
        #pragma unroll
        for (int j=0;j<4;j++) kvs[e0+j][d] = (f16)(s[j] * (1.0f/4096.0f));
    }
    __syncthreads();

    f32x4 acc[2][2];
    #pragma unroll
    for (int i=0;i<2;i++)
        #pragma unroll
        for (int j=0;j<2;j++) acc[i][j] = (f32x4){0.f,0.f,0.f,0.f};

    f16x8 a[2], bb[2];
    #pragma unroll
    for (int fr=0; fr<2; fr++)
        a[fr] = *reinterpret_cast<const f16x8*>(qb + ((size_t)bh*HW_ + row0 + fr*16 + lr)*HEADC + kg*8);
    #pragma unroll
    for (int fc=0; fc<2; fc++)
        bb[fc] = *reinterpret_cast<const f16x8*>(&kvs[fc*16 + lr][kg*8]);
    #pragma unroll
    for (int fr=0; fr<2; fr++)
        #pragma unroll
        for (int fc=0; fc<2; fc++)
            acc[fr][fc] = __builtin_amdgcn_mfma_f32_16x16x32_f16(a[fr], bb[fc], acc[fr][fc], 0, 0, 0);

    #pragma unroll
    for (int fr=0; fr<2; fr++)
    #pragma unroll
    for (int fc=0; fc<2; fc++)
    #pragma unroll
    for (int r=0; r<4; r++)
        Ls[wid*32 + fr*16 + kg*4 + r][fc*16 + lr] = (f16)acc[fr][fc][r];
    __syncthreads();

    int row = tid >> 1, hf = tid & 1;
    size_t base = ((size_t)b*HW_ + chunk*128 + row)*MIDC + h*HEADC + hf*16;
    f16x8 x0 = *reinterpret_cast<const f16x8*>(xb + base);
    f16x8 x1 = *reinterpret_cast<const f16x8*>(xb + base + 8);
    f16x8 s0 = *reinterpret_cast<const f16x8*>(&Ls[row][hf*16]);
    f16x8 s1 = *reinterpret_cast<const f16x8*>(&Ls[row][hf*16 + 8]);
    f16x8 o0, o1;
    #pragma unroll
    for (int j=0;j<8;j++){
        o0[j] = (f16)((float)s0[j] + (float)x0[j]);
        o1[j] = (f16)((float)s1[j] + (float)x1[j]);
    }
    *reinterpret_cast<f16x8*>(ret + base)     = o0;
    *reinterpret_cast<f16x8*>(ret + base + 8) = o1;
}

extern "C" void kernel_launch(void* const* d_in, const int* in_sizes, int n_in,
                              void* d_out, int out_size, void* d_ws, size_t ws_size,
                              hipStream_t stream) {
    const float* x     = (const float*)d_in[0];
    const float* w_qkv = (const float*)d_in[1];
    const float* b_qkv = (const float*)d_in[2];
    const float* kln_g = (const float*)d_in[3];
    const float* kln_b = (const float*)d_in[4];
    const float* vln_g = (const float*)d_in[5];
    const float* vln_b = (const float*)d_in[6];
    const float* w1    = (const float*)d_in[7];
    const float* b1    = (const float*)d_in[8];
    const float* w2    = (const float*)d_in[9];
    const float* b2    = (const float*)d_in[10];
    float* out = (float*)d_out;

    char* ws = (char*)d_ws;
    size_t off = 0;
    auto alloc = [&](size_t bytes) -> void* {
        void* p = ws + off; off += (bytes + 255) & ~255ULL; return p;
    };
    const size_t TOKB = (size_t)NTOK*MIDC*sizeof(f16); // 16.78 MB
    f16* xb    = (f16*)alloc(TOKB);               // preserved (residuals)
    f16* wqkvT = (f16*)alloc(768*256*sizeof(f16));
    f16* w1T   = (f16*)alloc(256*256*sizeof(f16));
    f16* w2T   = (f16*)alloc(256*256*sizeof(f16));
    float* pb  = (float*)alloc(768*sizeof(float));
    f16* qb    = (f16*)alloc(TOKB);
    f16* kb    = (f16*)alloc(TOKB);               // reused as h after k_kv
    f16* vb    = (f16*)alloc(TOKB);               // reused as ret after k_kv
    float* kvpart = (float*)alloc((size_t)64*16*1024*sizeof(float)); // 4 MB
    f16* retb = vb;
    f16* hb   = kb;

    // 1. merged convert + weight prep
    k_init<<<dim3(9475), 256, 0, stream>>>(x, w_qkv, w1, w2, b_qkv, xb, wqkvT, w1T, w2T, pb);

    // 2. QKV GEMM + bias + LN(k,v) + coalesced scatter
    k_gemm0<<<dim3(6, NTOK/128), 256, 0, stream>>>(
        xb, wqkvT, pb, kln_g, kln_b, vln_g, vln_b, qb, kb, vb);

    // 3. kv partials
    k_kv<<<dim3(64, HW_/256), 256, 0, stream>>>(kb, vb, kvpart);

    // 4. attn (+fused kv reduce) + residual(xb) -> ret f16 (into vb space)
    k_attn<<<dim3(64, HW_/128), 256, 0, stream>>>(qb, kvpart, xb, retb);

    // 5. MLP1 (+GELU) -> h (into kb space)
    k_mlp<1><<<dim3(4, NTOK/128), 256, 0, stream>>>(
        retb, w1T, b1, hb, nullptr, nullptr);

    // 6. MLP2 (+bias +resid xb) -> f32 out
    k_mlp<2><<<dim3(4, NTOK/128), 256, 0, stream>>>(
        hb, w2T, b2, nullptr, xb, out);
}